// Round 21
// baseline (225.529 us; speedup 1.0000x reference)
//
#include <hip/hip_runtime.h>

#define TOK    18464      // 32*577 tokens
#define SEQ    577
#define EMB    768
#define NH     12
#define HD     64
#define HEADSZ 36928      // SEQ*HD
#define PLANE  14180352   // TOK*768
#define SPAD   640        // padded seq stride for V^T

typedef float f32x4 __attribute__((ext_vector_type(4)));
typedef short s16x8 __attribute__((ext_vector_type(8)));

__device__ __forceinline__ unsigned short f2bf(float f) {
  unsigned u = __builtin_bit_cast(unsigned, f);
  return (unsigned short)((u + 0x7fffu + ((u >> 16) & 1u)) >> 16);
}
__device__ __forceinline__ unsigned pk2bf(float a, float b) {
  return (unsigned)f2bf(a) | ((unsigned)f2bf(b) << 16);
}
__device__ __forceinline__ float fexp2(float x) {
  float r; asm("v_exp_f32 %0, %1" : "=v"(r) : "v"(x)); return r;
}

__device__ __forceinline__ void gload16(const void* g, void* l) {
  __builtin_amdgcn_global_load_lds(
      (const __attribute__((address_space(1))) void*)g,
      (__attribute__((address_space(3))) void*)l, 16, 0, 0);
}

__device__ __forceinline__ void cvt8(const float* __restrict__ s, short* __restrict__ d) {
  const float4* s4 = reinterpret_cast<const float4*>(s);
  float4 a = s4[0], b = s4[1];
  s16x8 o;
  o[0] = (short)f2bf(a.x); o[1] = (short)f2bf(a.y);
  o[2] = (short)f2bf(a.z); o[3] = (short)f2bf(a.w);
  o[4] = (short)f2bf(b.x); o[5] = (short)f2bf(b.y);
  o[6] = (short)f2bf(b.z); o[7] = (short)f2bf(b.w);
  *reinterpret_cast<s16x8*>(d) = o;
}

// ---------------- fused prologue: x->bf16, weights->bf16, V^T pad-zero ----------
// R19 BUG FIX: x has 1,772,544 groups of 8 floats (not 221,568).
// [0, 1772544):            x (8 floats per thread)
// [1772544, 2067456):      wq|wk|wv -> wqkv, w_proj -> wpb (8 floats per thread)
// [2067456, 2264064):      zero vtb rows s in [576,640)  (16B per thread)
// grid = 8844 * 256 = 2,264,064 threads exactly.
__global__ void prologue(const float* __restrict__ x,
                         const float* __restrict__ wq, const float* __restrict__ wk,
                         const float* __restrict__ wv, const float* __restrict__ wp,
                         short* __restrict__ xb, short* __restrict__ wqkv,
                         short* __restrict__ wpb, short* __restrict__ vt) {
  int tid = blockIdx.x * blockDim.x + threadIdx.x;
  if (tid < 1772544) {
    cvt8(x + (size_t)tid * 8, xb + (size_t)tid * 8);
    return;
  }
  if (tid < 2067456) {
    int t = tid - 1772544;
    int region = t / 73728;
    int off = (t % 73728) * 8;
    const float* s; short* d;
    if (region == 0)      { s = wq + off; d = wqkv + off; }
    else if (region == 1) { s = wk + off; d = wqkv + 589824 + off; }
    else if (region == 2) { s = wv + off; d = wqkv + 2 * 589824 + off; }
    else                  { s = wp + off; d = wpb + off; }
    cvt8(s, d);
    return;
  }
  {
    int t = tid - 2067456;                           // 0..196607
    int row = t >> 3, c = t & 7;                     // 24576 rows x 8 chunks
    s16x8 z = {0, 0, 0, 0, 0, 0, 0, 0};
    *reinterpret_cast<s16x8*>((char*)vt + (size_t)row * 1280 + 1152 + c * 16) = z;
  }
}

// ---------------- 128x128 bf16 GEMM, BK=64, 8 waves (2-phase optimum) ------------
// BK64, XOR swizzle (0 conflicts), 64x32 out/wave -> ~100 unified regs ->
// 4 waves/SIMD, 47% occupancy, 115.5us measured (~570 TF = 2-phase ceiling).
// MODE 0: C -> Q,K planes [B][H][S][D] bf16 + V transposed [B][H][D][SPAD] bf16
template <int MODE>
__launch_bounds__(512)
__global__ void gemm128(const short* __restrict__ A, const short* __restrict__ Bw,
                        short* __restrict__ qk_out, short* __restrict__ vt_out,
                        float* __restrict__ out, const float* __restrict__ bias,
                        int M, int nnt) {
  __shared__ char Asb[16384];   // [128 rows][128B], XOR-swizzled storage
  __shared__ char Bsb[16384];
  int bid = blockIdx.x, nwg = gridDim.x;
  int qq = nwg >> 3, rr = nwg & 7;
  int xcd = bid & 7, loc = bid >> 3;
  int wgid = (xcd < rr ? xcd * (qq + 1) : rr * (qq + 1) + (xcd - rr) * qq) + loc;
  int tn = wgid % nnt;
  int tm = wgid / nnt;
  int tid = threadIdx.x;
  int w = tid >> 6, lane = tid & 63;
  int wm = w >> 2, wn = w & 3;          // 2 x 4 wave grid, 64x32 out each
  int lr = lane & 15, lg = lane >> 4;
  int m0 = tm * 128, n0 = tn * 128;

  f32x4 acc[4][2] = {};

  int srow = tid >> 3;                  // 0..63
  int scb  = (tid & 7) * 16;
  int cbs  = scb ^ ((srow & 7) << 4);
  const char* Ab = (const char*)A;
  const char* Bb = (const char*)Bw;
  int swz = (lr & 7) << 4;

  for (int kt = 0; kt < 12; ++kt) {
    size_t kbB = (size_t)kt * 128;
    __syncthreads();
    #pragma unroll
    for (int it = 0; it < 2; ++it) {
      int row = srow + it * 64;
      int gr = m0 + row; if (gr >= M) gr = M - 1;
      gload16(Ab + (size_t)gr * (EMB * 2) + kbB + cbs, Asb + row * 128 + scb);
      int rb = n0 + row;
      gload16(Bb + (size_t)rb * (EMB * 2) + kbB + cbs, Bsb + row * 128 + scb);
    }
    __syncthreads();

    #pragma unroll
    for (int kk = 0; kk < 2; ++kk) {
      int cb = (kk * 64 + lg * 16) ^ swz;
      s16x8 af[4], bfr[2];
      #pragma unroll
      for (int f = 0; f < 4; ++f)
        af[f] = *reinterpret_cast<const s16x8*>(Asb + (wm * 64 + f * 16 + lr) * 128 + cb);
      #pragma unroll
      for (int f = 0; f < 2; ++f)
        bfr[f] = *reinterpret_cast<const s16x8*>(Bsb + (wn * 32 + f * 16 + lr) * 128 + cb);
      #pragma unroll
      for (int i = 0; i < 4; ++i)
        #pragma unroll
        for (int j = 0; j < 2; ++j)
          acc[i][j] = __builtin_amdgcn_mfma_f32_16x16x32_bf16(af[i], bfr[j], acc[i][j], 0, 0, 0);
    }
  }

  int mbase = m0 + wm * 64;
  int nbase = n0 + wn * 32;
  #pragma unroll
  for (int i = 0; i < 4; ++i) {
    #pragma unroll
    for (int j = 0; j < 2; ++j) {
      #pragma unroll
      for (int r = 0; r < 4; ++r) {
        int row = mbase + i * 16 + lg * 4 + r;
        int col = nbase + j * 16 + lr;
        if (row < M) {
          float v = acc[i][j][r];
          if (MODE == 0) {
            int b = row / SEQ;
            int s = row - b * SEQ;
            if (col >= 1536) {        // V -> transposed [bh][d][SPAD]
              int rem = col - 1536;
              int h = rem >> 6, d = rem & 63;
              vt_out[((size_t)(b * NH + h) * HD + d) * SPAD + s] = (short)f2bf(v);
            } else {                  // Q,K planes [bh][s][d]
              int which = (col >= 768) ? 1 : 0;
              int rem = col - which * 768;
              int h = rem >> 6, d = rem & 63;
              qk_out[(size_t)which * PLANE + ((size_t)b * NH + h) * HEADSZ + s * HD + d] =
                  (short)f2bf(v);
            }
          } else {
            out[(size_t)row * EMB + col] = v + bias[col];
          }
        }
      }
    }
  }
}

// ---------------- 256x128 bf16 GEMM, BK=64, 8 waves (out-proj) ----------------
template <int MODE>
__launch_bounds__(512)
__global__ void gemm256(const short* __restrict__ A, const short* __restrict__ Bw,
                        short* __restrict__ qk_out, short* __restrict__ vt_out,
                        float* __restrict__ out, const float* __restrict__ bias,
                        int M, int nnt) {
  __shared__ char Asb[32768];   // [256 rows][128B], XOR-swizzled storage
  __shared__ char Bsb[16384];   // [128 rows][128B]
  int bid = blockIdx.x, nwg = gridDim.x;
  int qq = nwg >> 3, rr = nwg & 7;
  int xcd = bid & 7, loc = bid >> 3;
  int wgid = (xcd < rr ? xcd * (qq + 1) : rr * (qq + 1) + (xcd - rr) * qq) + loc;
  int tn = wgid % nnt;
  int tm = wgid / nnt;
  int tid = threadIdx.x;
  int w = tid >> 6, lane = tid & 63;
  int wm = w >> 1, wn = w & 1;          // 4 x 2 wave grid, 64x64 out each
  int lr = lane & 15, lg = lane >> 4;
  int m0 = tm * 256, n0 = tn * 128;

  f32x4 acc[4][4] = {};

  int srow = tid >> 3;                  // 0..63
  int scb  = (tid & 7) * 16;
  int cbs  = scb ^ ((srow & 7) << 4);
  const char* Ab = (const char*)A;
  const char* Bb = (const char*)Bw;
  int swz = (lr & 7) << 4;

  for (int kt = 0; kt < 12; ++kt) {
    size_t kbB = (size_t)kt * 128;
    __syncthreads();
    #pragma unroll
    for (int it = 0; it < 4; ++it) {         // A: 256 rows
      int row = srow + it * 64;
      int gr = m0 + row; if (gr >= M) gr = M - 1;
      gload16(Ab + (size_t)gr * (EMB * 2) + kbB + cbs, Asb + row * 128 + scb);
    }
    #pragma unroll
    for (int it = 0; it < 2; ++it) {         // B: 128 rows
      int row = srow + it * 64;
      int rb = n0 + row;
      gload16(Bb + (size_t)rb * (EMB * 2) + kbB + cbs, Bsb + row * 128 + scb);
    }
    __syncthreads();

    #pragma unroll
    for (int kk = 0; kk < 2; ++kk) {
      int cb = (kk * 64 + lg * 16) ^ swz;
      s16x8 af[4], bfr[4];
      #pragma unroll
      for (int f = 0; f < 4; ++f)
        af[f] = *reinterpret_cast<const s16x8*>(Asb + (wm * 64 + f * 16 + lr) * 128 + cb);
      #pragma unroll
      for (int f = 0; f < 4; ++f)
        bfr[f] = *reinterpret_cast<const s16x8*>(Bsb + (wn * 64 + f * 16 + lr) * 128 + cb);
      #pragma unroll
      for (int i = 0; i < 4; ++i)
        #pragma unroll
        for (int j = 0; j < 4; ++j)
          acc[i][j] = __builtin_amdgcn_mfma_f32_16x16x32_bf16(af[i], bfr[j], acc[i][j], 0, 0, 0);
    }
  }

  int mbase = m0 + wm * 64;
  int nbase = n0 + wn * 64;
  #pragma unroll
  for (int i = 0; i < 4; ++i) {
    #pragma unroll
    for (int j = 0; j < 4; ++j) {
      #pragma unroll
      for (int r = 0; r < 4; ++r) {
        int row = mbase + i * 16 + lg * 4 + r;
        int col = nbase + j * 16 + lr;
        if (row < M) {
          float v = acc[i][j][r];
          if (MODE == 0) {
            int b = row / SEQ;
            int s = row - b * SEQ;
            if (col >= 1536) {
              int rem = col - 1536;
              int h = rem >> 6, d = rem & 63;
              vt_out[((size_t)(b * NH + h) * HD + d) * SPAD + s] = (short)f2bf(v);
            } else {
              int which = (col >= 768) ? 1 : 0;
              int rem = col - which * 768;
              int h = rem >> 6, d = rem & 63;
              qk_out[(size_t)which * PLANE + ((size_t)b * NH + h) * HEADSZ + s * HD + d] =
                  (short)f2bf(v);
            }
          } else {
            out[(size_t)row * EMB + col] = v + bias[col];
          }
        }
      }
    }
  }
}

// ---------------- flash attention: KVBLK=128 (R16 optimum, verbatim) ----------------
__launch_bounds__(256)
__global__ void attn(const short* __restrict__ qkv, const short* __restrict__ vt,
                     short* __restrict__ cat) {
  int bid = blockIdx.x;
  int wgid = (bid & 7) * 240 + (bid >> 3);   // 1920 = 8*240, bijective
  int bh = wgid / 5, qt = wgid % 5;
  int b = bh / NH, h = bh % NH;
  const short* Q   = qkv + (size_t)bh * HEADSZ;
  const char* KpB  = (const char*)(qkv + (size_t)PLANE + (size_t)bh * HEADSZ);
  const char* VtpB = (const char*)(vt + (size_t)bh * (HD * SPAD));

  __shared__ char KVs[32768];        // K[128][128B] @0 | V sub0 [64][128B] @16K | sub1 @24K
  __shared__ short Pl[4][32 * 72];

  int tid = threadIdx.x, w = tid >> 6, lane = tid & 63;
  int lr = lane & 15, lg = lane >> 4;
  int q0 = qt * 128;
  short* Pw = &Pl[w][0];

  s16x8 qf[2][2];
  #pragma unroll
  for (int rb = 0; rb < 2; ++rb) {
    int row = q0 + w * 32 + rb * 16 + lr; if (row >= SEQ) row = SEQ - 1;
    #pragma unroll
    for (int kk = 0; kk < 2; ++kk)
      qf[rb][kk] = *reinterpret_cast<const s16x8*>(&Q[row * HD + kk * 32 + lg * 8]);
  }

  int srow = tid >> 3;                  // 0..31
  int scb  = (tid & 7) * 16;
  int scbs = scb ^ ((srow & 7) << 4);
  int swz  = (lr & 7) << 4;
  int ka0  = lr * 128 + ((lg * 16) ^ swz);

  f32x4 acco[2][4] = {};
  float lsum[2] = {0.f, 0.f};
  const float SCL = 0.18033688f;   // 0.125 * log2(e)
  const f32x4 NEG16 = {-16.f, -16.f, -16.f, -16.f};

  for (int tt = 0; tt < 5; ++tt) {
    int t0 = tt * 128;

    __syncthreads();
    #pragma unroll
    for (int it = 0; it < 4; ++it) {
      int row = srow + it * 32;
      int grow = t0 + row; if (grow > 576) grow = 576;
      gload16(KpB + (size_t)grow * 128 + scbs, KVs + row * 128 + scb);
    }
    #pragma unroll
    for (int it = 0; it < 4; ++it) {
      int vsub = it >> 1;
      int d = srow + (it & 1) * 32;
      gload16(VtpB + (size_t)d * 1280 + (size_t)t0 * 2 + vsub * 128 + scbs,
              KVs + 16384 + vsub * 8192 + d * 128 + scb);
    }
    __syncthreads();

    #pragma unroll
    for (int hf = 0; hf < 2; ++hf) {
      const char* Ksb = KVs + hf * 8192;
      const char* Vsb = KVs + 16384 + hf * 8192;
      int t0h = t0 + hf * 64;

      #pragma unroll
      for (int fk = 0; fk < 4; ++fk) {
        s16x8 kf0 = *reinterpret_cast<const s16x8*>(Ksb + fk * 2048 + ka0);
        s16x8 kf1 = *reinterpret_cast<const s16x8*>(Ksb + fk * 2048 + (ka0 ^ 64));
        f32x4 s0 = NEG16, s1 = NEG16;
        s0 = __builtin_amdgcn_mfma_f32_16x16x32_bf16(kf0, qf[0][0], s0, 0, 0, 0);
        s0 = __builtin_amdgcn_mfma_f32_16x16x32_bf16(kf1, qf[0][1], s0, 0, 0, 0);
        s1 = __builtin_amdgcn_mfma_f32_16x16x32_bf16(kf0, qf[1][0], s1, 0, 0, 0);
        s1 = __builtin_amdgcn_mfma_f32_16x16x32_bf16(kf1, qf[1][1], s1, 0, 0, 0);
        #pragma unroll
        for (int r = 0; r < 4; ++r) {
          bool ok = (t0h + fk * 16 + lg * 4 + r) < SEQ;
          s0[r] = ok ? s0[r] * SCL : -1e30f;
          s1[r] = ok ? s1[r] * SCL : -1e30f;
        }
        {
          float p0 = fexp2(s0[0]), p1 = fexp2(s0[1]);
          float p2 = fexp2(s0[2]), p3 = fexp2(s0[3]);
          lsum[0] += (p0 + p1) + (p2 + p3);
          uint2 pk; pk.x = pk2bf(p0, p1); pk.y = pk2bf(p2, p3);
          *reinterpret_cast<uint2*>(&Pw[(size_t)lr * 72 + fk * 16 + lg * 4]) = pk;
        }
        {
          float p0 = fexp2(s1[0]), p1 = fexp2(s1[1]);
          float p2 = fexp2(s1[2]), p3 = fexp2(s1[3]);
          lsum[1] += (p0 + p1) + (p2 + p3);
          uint2 pk; pk.x = pk2bf(p0, p1); pk.y = pk2bf(p2, p3);
          *reinterpret_cast<uint2*>(&Pw[(size_t)(16 + lr) * 72 + fk * 16 + lg * 4]) = pk;
        }
      }

      s16x8 pf[2][2];
      #pragma unroll
      for (int rb = 0; rb < 2; ++rb)
        #pragma unroll
        for (int kk = 0; kk < 2; ++kk)
          pf[rb][kk] = *reinterpret_cast<const s16x8*>(&Pw[(rb * 16 + lr) * 72 + kk * 32 + lg * 8]);

      #pragma unroll
      for (int f = 0; f < 4; ++f) {
        s16x8 vf0 = *reinterpret_cast<const s16x8*>(Vsb + f * 2048 + ka0);
        s16x8 vf1 = *reinterpret_cast<const s16x8*>(Vsb + f * 2048 + (ka0 ^ 64));
        acco[0][f] = __builtin_amdgcn_mfma_f32_16x16x32_bf16(pf[0][0], vf0, acco[0][f], 0, 0, 0);
        acco[0][f] = __builtin_amdgcn_mfma_f32_16x16x32_bf16(pf[0][1], vf1, acco[0][f], 0, 0, 0);
        acco[1][f] = __builtin_amdgcn_mfma_f32_16x16x32_bf16(pf[1][0], vf0, acco[1][f], 0, 0, 0);
        acco[1][f] = __builtin_amdgcn_mfma_f32_16x16x32_bf16(pf[1][1], vf1, acco[1][f], 0, 0, 0);
      }
    }
  }

  #pragma unroll
  for (int rb = 0; rb < 2; ++rb) {
    lsum[rb] += __shfl_xor(lsum[rb], 16);
    lsum[rb] += __shfl_xor(lsum[rb], 32);
  }

  #pragma unroll
  for (int rb = 0; rb < 2; ++rb) {
    #pragma unroll
    for (int r = 0; r < 4; ++r) {
      float li = __shfl(lsum[rb], lg * 4 + r);
      int s = q0 + w * 32 + rb * 16 + lg * 4 + r;
      if (s < SEQ) {
        float inv = 1.0f / li;
        #pragma unroll
        for (int f = 0; f < 4; ++f)
          cat[((size_t)b * SEQ + s) * EMB + h * HD + f * 16 + lr] =
              (short)f2bf(acco[rb][f][r] * inv);
      }
    }
  }
}

extern "C" void kernel_launch(void* const* d_in, const int* in_sizes, int n_in,
                              void* d_out, int out_size, void* d_ws, size_t ws_size,
                              hipStream_t stream) {
  const float* x  = (const float*)d_in[0];
  const float* wq = (const float*)d_in[1];
  const float* wk = (const float*)d_in[2];
  const float* wv = (const float*)d_in[3];
  const float* wp = (const float*)d_in[4];
  const float* bp = (const float*)d_in[5];
  float* out = (float*)d_out;

  char* ws = (char*)d_ws;
  short* xb   = (short*)ws;                         // 28,360,704 B (reused as cat)
  short* wqkv = (short*)(ws + 28360704);            //  3,538,944 B
  short* wpb  = (short*)(ws + 31899648);            //  1,179,648 B
  short* qkb  = (short*)(ws + 33079296);            // 56,721,408 B (Q,K planes)
  short* vtb  = (short*)(ws + 89800704);            // 31,457,280 B (V^T [bh][d][640])
  short* cat  = xb;                                 // x dead after QKV GEMM

  prologue<<<8844, 256, 0, stream>>>(x, wq, wk, wv, wp, xb, wqkv, wpb, vtb);
  gemm128<0><<<145 * 18, 512, 0, stream>>>(xb, wqkv, qkb, vtb, nullptr, nullptr, TOK, 18);
  attn<<<1920, 256, 0, stream>>>(qkb, vtb, cat);
  gemm256<1><<<73 * 6, 512, 0, stream>>>(cat, wpb, nullptr, nullptr, out, bp, TOK, 6);
}

// Round 22
// 221.940 us; speedup vs baseline: 1.0162x; 1.0162x over previous
//
#include <hip/hip_runtime.h>

#define TOK    18464      // 32*577 tokens
#define SEQ    577
#define EMB    768
#define NH     12
#define HD     64
#define HEADSZ 36928      // SEQ*HD
#define PLANE  14180352   // TOK*768
#define SPAD   640        // padded seq stride for V^T

typedef float f32x4 __attribute__((ext_vector_type(4)));
typedef short s16x8 __attribute__((ext_vector_type(8)));

__device__ __forceinline__ unsigned short f2bf(float f) {
  unsigned u = __builtin_bit_cast(unsigned, f);
  return (unsigned short)((u + 0x7fffu + ((u >> 16) & 1u)) >> 16);
}
__device__ __forceinline__ unsigned pk2bf(float a, float b) {
  return (unsigned)f2bf(a) | ((unsigned)f2bf(b) << 16);
}
__device__ __forceinline__ float fexp2(float x) {
  float r; asm("v_exp_f32 %0, %1" : "=v"(r) : "v"(x)); return r;
}

__device__ __forceinline__ void gload16(const void* g, void* l) {
  __builtin_amdgcn_global_load_lds(
      (const __attribute__((address_space(1))) void*)g,
      (__attribute__((address_space(3))) void*)l, 16, 0, 0);
}

__device__ __forceinline__ void cvt8(const float* __restrict__ s, short* __restrict__ d) {
  const float4* s4 = reinterpret_cast<const float4*>(s);
  float4 a = s4[0], b = s4[1];
  s16x8 o;
  o[0] = (short)f2bf(a.x); o[1] = (short)f2bf(a.y);
  o[2] = (short)f2bf(a.z); o[3] = (short)f2bf(a.w);
  o[4] = (short)f2bf(b.x); o[5] = (short)f2bf(b.y);
  o[6] = (short)f2bf(b.z); o[7] = (short)f2bf(b.w);
  *reinterpret_cast<s16x8*>(d) = o;
}

// ---------------- fused prologue: x->bf16, weights->bf16, V^T pad-zero ----------
// [0, 1772544):            x (8 floats per thread)
// [1772544, 2067456):      wq|wk|wv -> wqkv, w_proj -> wpb (8 floats per thread)
// [2067456, 2264064):      zero vtb rows s in [576,640)  (16B per thread)
// grid = 8844 * 256 = 2,264,064 threads exactly.
__global__ void prologue(const float* __restrict__ x,
                         const float* __restrict__ wq, const float* __restrict__ wk,
                         const float* __restrict__ wv, const float* __restrict__ wp,
                         short* __restrict__ xb, short* __restrict__ wqkv,
                         short* __restrict__ wpb, short* __restrict__ vt) {
  int tid = blockIdx.x * blockDim.x + threadIdx.x;
  if (tid < 1772544) {
    cvt8(x + (size_t)tid * 8, xb + (size_t)tid * 8);
    return;
  }
  if (tid < 2067456) {
    int t = tid - 1772544;
    int region = t / 73728;
    int off = (t % 73728) * 8;
    const float* s; short* d;
    if (region == 0)      { s = wq + off; d = wqkv + off; }
    else if (region == 1) { s = wk + off; d = wqkv + 589824 + off; }
    else if (region == 2) { s = wv + off; d = wqkv + 2 * 589824 + off; }
    else                  { s = wp + off; d = wpb + off; }
    cvt8(s, d);
    return;
  }
  {
    int t = tid - 2067456;                           // 0..196607
    int row = t >> 3, c = t & 7;                     // 24576 rows x 8 chunks
    s16x8 z = {0, 0, 0, 0, 0, 0, 0, 0};
    *reinterpret_cast<s16x8*>((char*)vt + (size_t)row * 1280 + 1152 + c * 16) = z;
  }
}

// ---------------- 128x128 bf16 GEMM, BK=64, 8 waves (2-phase optimum) ------------
// BK64, XOR swizzle (0 conflicts), 64x32 out/wave -> ~100 unified regs ->
// 4 waves/SIMD, 47% occupancy, 115.5us measured (~570 TF = 2-phase ceiling).
// MODE 0: C -> Q,K planes [B][H][S][D] bf16 + V transposed [B][H][D][SPAD] bf16
template <int MODE>
__launch_bounds__(512)
__global__ void gemm128(const short* __restrict__ A, const short* __restrict__ Bw,
                        short* __restrict__ qk_out, short* __restrict__ vt_out,
                        float* __restrict__ out, const float* __restrict__ bias,
                        int M, int nnt) {
  __shared__ char Asb[16384];   // [128 rows][128B], XOR-swizzled storage
  __shared__ char Bsb[16384];
  int bid = blockIdx.x, nwg = gridDim.x;
  int qq = nwg >> 3, rr = nwg & 7;
  int xcd = bid & 7, loc = bid >> 3;
  int wgid = (xcd < rr ? xcd * (qq + 1) : rr * (qq + 1) + (xcd - rr) * qq) + loc;
  int tn = wgid % nnt;
  int tm = wgid / nnt;
  int tid = threadIdx.x;
  int w = tid >> 6, lane = tid & 63;
  int wm = w >> 2, wn = w & 3;          // 2 x 4 wave grid, 64x32 out each
  int lr = lane & 15, lg = lane >> 4;
  int m0 = tm * 128, n0 = tn * 128;

  f32x4 acc[4][2] = {};

  int srow = tid >> 3;                  // 0..63
  int scb  = (tid & 7) * 16;
  int cbs  = scb ^ ((srow & 7) << 4);
  const char* Ab = (const char*)A;
  const char* Bb = (const char*)Bw;
  int swz = (lr & 7) << 4;

  for (int kt = 0; kt < 12; ++kt) {
    size_t kbB = (size_t)kt * 128;
    __syncthreads();
    #pragma unroll
    for (int it = 0; it < 2; ++it) {
      int row = srow + it * 64;
      int gr = m0 + row; if (gr >= M) gr = M - 1;
      gload16(Ab + (size_t)gr * (EMB * 2) + kbB + cbs, Asb + row * 128 + scb);
      int rb = n0 + row;
      gload16(Bb + (size_t)rb * (EMB * 2) + kbB + cbs, Bsb + row * 128 + scb);
    }
    __syncthreads();

    #pragma unroll
    for (int kk = 0; kk < 2; ++kk) {
      int cb = (kk * 64 + lg * 16) ^ swz;
      s16x8 af[4], bfr[2];
      #pragma unroll
      for (int f = 0; f < 4; ++f)
        af[f] = *reinterpret_cast<const s16x8*>(Asb + (wm * 64 + f * 16 + lr) * 128 + cb);
      #pragma unroll
      for (int f = 0; f < 2; ++f)
        bfr[f] = *reinterpret_cast<const s16x8*>(Bsb + (wn * 32 + f * 16 + lr) * 128 + cb);
      #pragma unroll
      for (int i = 0; i < 4; ++i)
        #pragma unroll
        for (int j = 0; j < 2; ++j)
          acc[i][j] = __builtin_amdgcn_mfma_f32_16x16x32_bf16(af[i], bfr[j], acc[i][j], 0, 0, 0);
    }
  }

  int mbase = m0 + wm * 64;
  int nbase = n0 + wn * 32;
  #pragma unroll
  for (int i = 0; i < 4; ++i) {
    #pragma unroll
    for (int j = 0; j < 2; ++j) {
      #pragma unroll
      for (int r = 0; r < 4; ++r) {
        int row = mbase + i * 16 + lg * 4 + r;
        int col = nbase + j * 16 + lr;
        if (row < M) {
          float v = acc[i][j][r];
          if (MODE == 0) {
            int b = row / SEQ;
            int s = row - b * SEQ;
            if (col >= 1536) {        // V -> transposed [bh][d][SPAD]
              int rem = col - 1536;
              int h = rem >> 6, d = rem & 63;
              vt_out[((size_t)(b * NH + h) * HD + d) * SPAD + s] = (short)f2bf(v);
            } else {                  // Q,K planes [bh][s][d]
              int which = (col >= 768) ? 1 : 0;
              int rem = col - which * 768;
              int h = rem >> 6, d = rem & 63;
              qk_out[(size_t)which * PLANE + ((size_t)b * NH + h) * HEADSZ + s * HD + d] =
                  (short)f2bf(v);
            }
          } else {
            out[(size_t)row * EMB + col] = v + bias[col];
          }
        }
      }
    }
  }
}

// ---------------- 256x128 bf16 GEMM, BK=64, 8 waves (out-proj) ----------------
template <int MODE>
__launch_bounds__(512)
__global__ void gemm256(const short* __restrict__ A, const short* __restrict__ Bw,
                        short* __restrict__ qk_out, short* __restrict__ vt_out,
                        float* __restrict__ out, const float* __restrict__ bias,
                        int M, int nnt) {
  __shared__ char Asb[32768];   // [256 rows][128B], XOR-swizzled storage
  __shared__ char Bsb[16384];   // [128 rows][128B]
  int bid = blockIdx.x, nwg = gridDim.x;
  int qq = nwg >> 3, rr = nwg & 7;
  int xcd = bid & 7, loc = bid >> 3;
  int wgid = (xcd < rr ? xcd * (qq + 1) : rr * (qq + 1) + (xcd - rr) * qq) + loc;
  int tn = wgid % nnt;
  int tm = wgid / nnt;
  int tid = threadIdx.x;
  int w = tid >> 6, lane = tid & 63;
  int wm = w >> 1, wn = w & 1;          // 4 x 2 wave grid, 64x64 out each
  int lr = lane & 15, lg = lane >> 4;
  int m0 = tm * 256, n0 = tn * 128;

  f32x4 acc[4][4] = {};

  int srow = tid >> 3;                  // 0..63
  int scb  = (tid & 7) * 16;
  int cbs  = scb ^ ((srow & 7) << 4);
  const char* Ab = (const char*)A;
  const char* Bb = (const char*)Bw;
  int swz = (lr & 7) << 4;

  for (int kt = 0; kt < 12; ++kt) {
    size_t kbB = (size_t)kt * 128;
    __syncthreads();
    #pragma unroll
    for (int it = 0; it < 4; ++it) {         // A: 256 rows
      int row = srow + it * 64;
      int gr = m0 + row; if (gr >= M) gr = M - 1;
      gload16(Ab + (size_t)gr * (EMB * 2) + kbB + cbs, Asb + row * 128 + scb);
    }
    #pragma unroll
    for (int it = 0; it < 2; ++it) {         // B: 128 rows
      int row = srow + it * 64;
      int rb = n0 + row;
      gload16(Bb + (size_t)rb * (EMB * 2) + kbB + cbs, Bsb + row * 128 + scb);
    }
    __syncthreads();

    #pragma unroll
    for (int kk = 0; kk < 2; ++kk) {
      int cb = (kk * 64 + lg * 16) ^ swz;
      s16x8 af[4], bfr[4];
      #pragma unroll
      for (int f = 0; f < 4; ++f)
        af[f] = *reinterpret_cast<const s16x8*>(Asb + (wm * 64 + f * 16 + lr) * 128 + cb);
      #pragma unroll
      for (int f = 0; f < 4; ++f)
        bfr[f] = *reinterpret_cast<const s16x8*>(Bsb + (wn * 64 + f * 16 + lr) * 128 + cb);
      #pragma unroll
      for (int i = 0; i < 4; ++i)
        #pragma unroll
        for (int j = 0; j < 4; ++j)
          acc[i][j] = __builtin_amdgcn_mfma_f32_16x16x32_bf16(af[i], bfr[j], acc[i][j], 0, 0, 0);
    }
  }

  int mbase = m0 + wm * 64;
  int nbase = n0 + wn * 64;
  #pragma unroll
  for (int i = 0; i < 4; ++i) {
    #pragma unroll
    for (int j = 0; j < 4; ++j) {
      #pragma unroll
      for (int r = 0; r < 4; ++r) {
        int row = mbase + i * 16 + lg * 4 + r;
        int col = nbase + j * 16 + lr;
        if (row < M) {
          float v = acc[i][j][r];
          if (MODE == 0) {
            int b = row / SEQ;
            int s = row - b * SEQ;
            if (col >= 1536) {
              int rem = col - 1536;
              int h = rem >> 6, d = rem & 63;
              vt_out[((size_t)(b * NH + h) * HD + d) * SPAD + s] = (short)f2bf(v);
            } else {
              int which = (col >= 768) ? 1 : 0;
              int rem = col - which * 768;
              int h = rem >> 6, d = rem & 63;
              qk_out[(size_t)which * PLANE + ((size_t)b * NH + h) * HEADSZ + s * HD + d] =
                  (short)f2bf(v);
            }
          } else {
            out[(size_t)row * EMB + col] = v + bias[col];
          }
        }
      }
    }
  }
}

// ---------------- flash attention: KVBLK=128 + T5 setprio around MFMA bursts -----
__launch_bounds__(256)
__global__ void attn(const short* __restrict__ qkv, const short* __restrict__ vt,
                     short* __restrict__ cat) {
  int bid = blockIdx.x;
  int wgid = (bid & 7) * 240 + (bid >> 3);   // 1920 = 8*240, bijective
  int bh = wgid / 5, qt = wgid % 5;
  int b = bh / NH, h = bh % NH;
  const short* Q   = qkv + (size_t)bh * HEADSZ;
  const char* KpB  = (const char*)(qkv + (size_t)PLANE + (size_t)bh * HEADSZ);
  const char* VtpB = (const char*)(vt + (size_t)bh * (HD * SPAD));

  __shared__ char KVs[32768];        // K[128][128B] @0 | V sub0 [64][128B] @16K | sub1 @24K
  __shared__ short Pl[4][32 * 72];

  int tid = threadIdx.x, w = tid >> 6, lane = tid & 63;
  int lr = lane & 15, lg = lane >> 4;
  int q0 = qt * 128;
  short* Pw = &Pl[w][0];

  s16x8 qf[2][2];
  #pragma unroll
  for (int rb = 0; rb < 2; ++rb) {
    int row = q0 + w * 32 + rb * 16 + lr; if (row >= SEQ) row = SEQ - 1;
    #pragma unroll
    for (int kk = 0; kk < 2; ++kk)
      qf[rb][kk] = *reinterpret_cast<const s16x8*>(&Q[row * HD + kk * 32 + lg * 8]);
  }

  int srow = tid >> 3;                  // 0..31
  int scb  = (tid & 7) * 16;
  int scbs = scb ^ ((srow & 7) << 4);
  int swz  = (lr & 7) << 4;
  int ka0  = lr * 128 + ((lg * 16) ^ swz);

  f32x4 acco[2][4] = {};
  float lsum[2] = {0.f, 0.f};
  const float SCL = 0.18033688f;   // 0.125 * log2(e)
  const f32x4 NEG16 = {-16.f, -16.f, -16.f, -16.f};

  for (int tt = 0; tt < 5; ++tt) {
    int t0 = tt * 128;

    __syncthreads();
    #pragma unroll
    for (int it = 0; it < 4; ++it) {
      int row = srow + it * 32;
      int grow = t0 + row; if (grow > 576) grow = 576;
      gload16(KpB + (size_t)grow * 128 + scbs, KVs + row * 128 + scb);
    }
    #pragma unroll
    for (int it = 0; it < 4; ++it) {
      int vsub = it >> 1;
      int d = srow + (it & 1) * 32;
      gload16(VtpB + (size_t)d * 1280 + (size_t)t0 * 2 + vsub * 128 + scbs,
              KVs + 16384 + vsub * 8192 + d * 128 + scb);
    }
    __syncthreads();

    #pragma unroll
    for (int hf = 0; hf < 2; ++hf) {
      const char* Ksb = KVs + hf * 8192;
      const char* Vsb = KVs + 16384 + hf * 8192;
      int t0h = t0 + hf * 64;

      #pragma unroll
      for (int fk = 0; fk < 4; ++fk) {
        s16x8 kf0 = *reinterpret_cast<const s16x8*>(Ksb + fk * 2048 + ka0);
        s16x8 kf1 = *reinterpret_cast<const s16x8*>(Ksb + fk * 2048 + (ka0 ^ 64));
        f32x4 s0 = NEG16, s1 = NEG16;
        __builtin_amdgcn_s_setprio(1);            // T5: favor MFMA burst
        s0 = __builtin_amdgcn_mfma_f32_16x16x32_bf16(kf0, qf[0][0], s0, 0, 0, 0);
        s0 = __builtin_amdgcn_mfma_f32_16x16x32_bf16(kf1, qf[0][1], s0, 0, 0, 0);
        s1 = __builtin_amdgcn_mfma_f32_16x16x32_bf16(kf0, qf[1][0], s1, 0, 0, 0);
        s1 = __builtin_amdgcn_mfma_f32_16x16x32_bf16(kf1, qf[1][1], s1, 0, 0, 0);
        __builtin_amdgcn_s_setprio(0);
        #pragma unroll
        for (int r = 0; r < 4; ++r) {
          bool ok = (t0h + fk * 16 + lg * 4 + r) < SEQ;
          s0[r] = ok ? s0[r] * SCL : -1e30f;
          s1[r] = ok ? s1[r] * SCL : -1e30f;
        }
        {
          float p0 = fexp2(s0[0]), p1 = fexp2(s0[1]);
          float p2 = fexp2(s0[2]), p3 = fexp2(s0[3]);
          lsum[0] += (p0 + p1) + (p2 + p3);
          uint2 pk; pk.x = pk2bf(p0, p1); pk.y = pk2bf(p2, p3);
          *reinterpret_cast<uint2*>(&Pw[(size_t)lr * 72 + fk * 16 + lg * 4]) = pk;
        }
        {
          float p0 = fexp2(s1[0]), p1 = fexp2(s1[1]);
          float p2 = fexp2(s1[2]), p3 = fexp2(s1[3]);
          lsum[1] += (p0 + p1) + (p2 + p3);
          uint2 pk; pk.x = pk2bf(p0, p1); pk.y = pk2bf(p2, p3);
          *reinterpret_cast<uint2*>(&Pw[(size_t)(16 + lr) * 72 + fk * 16 + lg * 4]) = pk;
        }
      }

      s16x8 pf[2][2];
      #pragma unroll
      for (int rb = 0; rb < 2; ++rb)
        #pragma unroll
        for (int kk = 0; kk < 2; ++kk)
          pf[rb][kk] = *reinterpret_cast<const s16x8*>(&Pw[(rb * 16 + lr) * 72 + kk * 32 + lg * 8]);

      #pragma unroll
      for (int f = 0; f < 4; ++f) {
        s16x8 vf0 = *reinterpret_cast<const s16x8*>(Vsb + f * 2048 + ka0);
        s16x8 vf1 = *reinterpret_cast<const s16x8*>(Vsb + f * 2048 + (ka0 ^ 64));
        __builtin_amdgcn_s_setprio(1);            // T5: favor MFMA burst
        acco[0][f] = __builtin_amdgcn_mfma_f32_16x16x32_bf16(pf[0][0], vf0, acco[0][f], 0, 0, 0);
        acco[0][f] = __builtin_amdgcn_mfma_f32_16x16x32_bf16(pf[0][1], vf1, acco[0][f], 0, 0, 0);
        acco[1][f] = __builtin_amdgcn_mfma_f32_16x16x32_bf16(pf[1][0], vf0, acco[1][f], 0, 0, 0);
        acco[1][f] = __builtin_amdgcn_mfma_f32_16x16x32_bf16(pf[1][1], vf1, acco[1][f], 0, 0, 0);
        __builtin_amdgcn_s_setprio(0);
      }
    }
  }

  #pragma unroll
  for (int rb = 0; rb < 2; ++rb) {
    lsum[rb] += __shfl_xor(lsum[rb], 16);
    lsum[rb] += __shfl_xor(lsum[rb], 32);
  }

  #pragma unroll
  for (int rb = 0; rb < 2; ++rb) {
    #pragma unroll
    for (int r = 0; r < 4; ++r) {
      float li = __shfl(lsum[rb], lg * 4 + r);
      int s = q0 + w * 32 + rb * 16 + lg * 4 + r;
      if (s < SEQ) {
        float inv = 1.0f / li;
        #pragma unroll
        for (int f = 0; f < 4; ++f)
          cat[((size_t)b * SEQ + s) * EMB + h * HD + f * 16 + lr] =
              (short)f2bf(acco[rb][f][r] * inv);
      }
    }
  }
}

extern "C" void kernel_launch(void* const* d_in, const int* in_sizes, int n_in,
                              void* d_out, int out_size, void* d_ws, size_t ws_size,
                              hipStream_t stream) {
  const float* x  = (const float*)d_in[0];
  const float* wq = (const float*)d_in[1];
  const float* wk = (const float*)d_in[2];
  const float* wv = (const float*)d_in[3];
  const float* wp = (const float*)d_in[4];
  const float* bp = (const float*)d_in[5];
  float* out = (float*)d_out;

  char* ws = (char*)d_ws;
  short* xb   = (short*)ws;                         // 28,360,704 B (reused as cat)
  short* wqkv = (short*)(ws + 28360704);            //  3,538,944 B
  short* wpb  = (short*)(ws + 31899648);            //  1,179,648 B
  short* qkb  = (short*)(ws + 33079296);            // 56,721,408 B (Q,K planes)
  short* vtb  = (short*)(ws + 89800704);            // 31,457,280 B (V^T [bh][d][640])
  short* cat  = xb;                                 // x dead after QKV GEMM

  prologue<<<8844, 256, 0, stream>>>(x, wq, wk, wv, wp, xb, wqkv, wpb, vtb);
  gemm128<0><<<145 * 18, 512, 0, stream>>>(xb, wqkv, qkb, vtb, nullptr, nullptr, TOK, 18);
  attn<<<1920, 256, 0, stream>>>(qkb, vtb, cat);
  gemm256<1><<<73 * 6, 512, 0, stream>>>(cat, wpb, nullptr, nullptr, out, bp, TOK, 6);
}

// Round 23
// 219.392 us; speedup vs baseline: 1.0280x; 1.0116x over previous
//
#include <hip/hip_runtime.h>

#define TOK    18464      // 32*577 tokens
#define SEQ    577
#define EMB    768
#define NH     12
#define HD     64
#define HEADSZ 36928      // SEQ*HD
#define PLANE  14180352   // TOK*768
#define SPAD   640        // padded seq stride for V^T

typedef float f32x4 __attribute__((ext_vector_type(4)));
typedef short s16x8 __attribute__((ext_vector_type(8)));

__device__ __forceinline__ unsigned short f2bf(float f) {
  unsigned u = __builtin_bit_cast(unsigned, f);
  return (unsigned short)((u + 0x7fffu + ((u >> 16) & 1u)) >> 16);
}
__device__ __forceinline__ unsigned pk2bf(float a, float b) {
  return (unsigned)f2bf(a) | ((unsigned)f2bf(b) << 16);
}
__device__ __forceinline__ float fexp2(float x) {
  float r; asm("v_exp_f32 %0, %1" : "=v"(r) : "v"(x)); return r;
}

__device__ __forceinline__ void gload16(const void* g, void* l) {
  __builtin_amdgcn_global_load_lds(
      (const __attribute__((address_space(1))) void*)g,
      (__attribute__((address_space(3))) void*)l, 16, 0, 0);
}

__device__ __forceinline__ void cvt8(const float* __restrict__ s, short* __restrict__ d) {
  const float4* s4 = reinterpret_cast<const float4*>(s);
  float4 a = s4[0], b = s4[1];
  s16x8 o;
  o[0] = (short)f2bf(a.x); o[1] = (short)f2bf(a.y);
  o[2] = (short)f2bf(a.z); o[3] = (short)f2bf(a.w);
  o[4] = (short)f2bf(b.x); o[5] = (short)f2bf(b.y);
  o[6] = (short)f2bf(b.z); o[7] = (short)f2bf(b.w);
  *reinterpret_cast<s16x8*>(d) = o;
}

// ---------------- fused prologue: x->bf16, weights->bf16, V^T pad-zero ----------
// [0, 1772544):            x (8 floats per thread)
// [1772544, 2067456):      wq|wk|wv -> wqkv, w_proj -> wpb (8 floats per thread)
// [2067456, 2264064):      zero vtb rows s in [576,640)  (16B per thread)
// grid = 8844 * 256 = 2,264,064 threads exactly.
__global__ void prologue(const float* __restrict__ x,
                         const float* __restrict__ wq, const float* __restrict__ wk,
                         const float* __restrict__ wv, const float* __restrict__ wp,
                         short* __restrict__ xb, short* __restrict__ wqkv,
                         short* __restrict__ wpb, short* __restrict__ vt) {
  int tid = blockIdx.x * blockDim.x + threadIdx.x;
  if (tid < 1772544) {
    cvt8(x + (size_t)tid * 8, xb + (size_t)tid * 8);
    return;
  }
  if (tid < 2067456) {
    int t = tid - 1772544;
    int region = t / 73728;
    int off = (t % 73728) * 8;
    const float* s; short* d;
    if (region == 0)      { s = wq + off; d = wqkv + off; }
    else if (region == 1) { s = wk + off; d = wqkv + 589824 + off; }
    else if (region == 2) { s = wv + off; d = wqkv + 2 * 589824 + off; }
    else                  { s = wp + off; d = wpb + off; }
    cvt8(s, d);
    return;
  }
  {
    int t = tid - 2067456;                           // 0..196607
    int row = t >> 3, c = t & 7;                     // 24576 rows x 8 chunks
    s16x8 z = {0, 0, 0, 0, 0, 0, 0, 0};
    *reinterpret_cast<s16x8*>((char*)vt + (size_t)row * 1280 + 1152 + c * 16) = z;
  }
}

// ---------------- 128x128 bf16 GEMM, BK=64, 8 waves (2-phase optimum) ------------
// BK64, XOR swizzle (0 conflicts), 64x32 out/wave -> ~100 unified regs ->
// 4 waves/SIMD, 47% occupancy, 115.5us measured (~570 TF = 2-phase ceiling).
// MODE 0: C -> Q (prescaled by 0.125*log2e), K planes [B][H][S][D] bf16
//         + V transposed [B][H][D][SPAD] bf16
template <int MODE>
__launch_bounds__(512)
__global__ void gemm128(const short* __restrict__ A, const short* __restrict__ Bw,
                        short* __restrict__ qk_out, short* __restrict__ vt_out,
                        float* __restrict__ out, const float* __restrict__ bias,
                        int M, int nnt) {
  __shared__ char Asb[16384];   // [128 rows][128B], XOR-swizzled storage
  __shared__ char Bsb[16384];
  int bid = blockIdx.x, nwg = gridDim.x;
  int qq = nwg >> 3, rr = nwg & 7;
  int xcd = bid & 7, loc = bid >> 3;
  int wgid = (xcd < rr ? xcd * (qq + 1) : rr * (qq + 1) + (xcd - rr) * qq) + loc;
  int tn = wgid % nnt;
  int tm = wgid / nnt;
  int tid = threadIdx.x;
  int w = tid >> 6, lane = tid & 63;
  int wm = w >> 2, wn = w & 3;          // 2 x 4 wave grid, 64x32 out each
  int lr = lane & 15, lg = lane >> 4;
  int m0 = tm * 128, n0 = tn * 128;

  f32x4 acc[4][2] = {};

  int srow = tid >> 3;                  // 0..63
  int scb  = (tid & 7) * 16;
  int cbs  = scb ^ ((srow & 7) << 4);
  const char* Ab = (const char*)A;
  const char* Bb = (const char*)Bw;
  int swz = (lr & 7) << 4;

  for (int kt = 0; kt < 12; ++kt) {
    size_t kbB = (size_t)kt * 128;
    __syncthreads();
    #pragma unroll
    for (int it = 0; it < 2; ++it) {
      int row = srow + it * 64;
      int gr = m0 + row; if (gr >= M) gr = M - 1;
      gload16(Ab + (size_t)gr * (EMB * 2) + kbB + cbs, Asb + row * 128 + scb);
      int rb = n0 + row;
      gload16(Bb + (size_t)rb * (EMB * 2) + kbB + cbs, Bsb + row * 128 + scb);
    }
    __syncthreads();

    #pragma unroll
    for (int kk = 0; kk < 2; ++kk) {
      int cb = (kk * 64 + lg * 16) ^ swz;
      s16x8 af[4], bfr[2];
      #pragma unroll
      for (int f = 0; f < 4; ++f)
        af[f] = *reinterpret_cast<const s16x8*>(Asb + (wm * 64 + f * 16 + lr) * 128 + cb);
      #pragma unroll
      for (int f = 0; f < 2; ++f)
        bfr[f] = *reinterpret_cast<const s16x8*>(Bsb + (wn * 32 + f * 16 + lr) * 128 + cb);
      #pragma unroll
      for (int i = 0; i < 4; ++i)
        #pragma unroll
        for (int j = 0; j < 2; ++j)
          acc[i][j] = __builtin_amdgcn_mfma_f32_16x16x32_bf16(af[i], bfr[j], acc[i][j], 0, 0, 0);
    }
  }

  int mbase = m0 + wm * 64;
  int nbase = n0 + wn * 32;
  #pragma unroll
  for (int i = 0; i < 4; ++i) {
    #pragma unroll
    for (int j = 0; j < 2; ++j) {
      #pragma unroll
      for (int r = 0; r < 4; ++r) {
        int row = mbase + i * 16 + lg * 4 + r;
        int col = nbase + j * 16 + lr;
        if (row < M) {
          float v = acc[i][j][r];
          if (MODE == 0) {
            int b = row / SEQ;
            int s = row - b * SEQ;
            if (col >= 1536) {        // V -> transposed [bh][d][SPAD]
              int rem = col - 1536;
              int h = rem >> 6, d = rem & 63;
              vt_out[((size_t)(b * NH + h) * HD + d) * SPAD + s] = (short)f2bf(v);
            } else {                  // Q,K planes [bh][s][d]; Q prescaled
              int which = (col >= 768) ? 1 : 0;
              if (which == 0) v *= 0.18033688f;   // 0.125 * log2(e)
              int rem = col - which * 768;
              int h = rem >> 6, d = rem & 63;
              qk_out[(size_t)which * PLANE + ((size_t)b * NH + h) * HEADSZ + s * HD + d] =
                  (short)f2bf(v);
            }
          } else {
            out[(size_t)row * EMB + col] = v + bias[col];
          }
        }
      }
    }
  }
}

// ---------------- 256x128 bf16 GEMM, BK=64, 8 waves (out-proj) ----------------
template <int MODE>
__launch_bounds__(512)
__global__ void gemm256(const short* __restrict__ A, const short* __restrict__ Bw,
                        short* __restrict__ qk_out, short* __restrict__ vt_out,
                        float* __restrict__ out, const float* __restrict__ bias,
                        int M, int nnt) {
  __shared__ char Asb[32768];   // [256 rows][128B], XOR-swizzled storage
  __shared__ char Bsb[16384];   // [128 rows][128B]
  int bid = blockIdx.x, nwg = gridDim.x;
  int qq = nwg >> 3, rr = nwg & 7;
  int xcd = bid & 7, loc = bid >> 3;
  int wgid = (xcd < rr ? xcd * (qq + 1) : rr * (qq + 1) + (xcd - rr) * qq) + loc;
  int tn = wgid % nnt;
  int tm = wgid / nnt;
  int tid = threadIdx.x;
  int w = tid >> 6, lane = tid & 63;
  int wm = w >> 1, wn = w & 1;          // 4 x 2 wave grid, 64x64 out each
  int lr = lane & 15, lg = lane >> 4;
  int m0 = tm * 256, n0 = tn * 128;

  f32x4 acc[4][4] = {};

  int srow = tid >> 3;                  // 0..63
  int scb  = (tid & 7) * 16;
  int cbs  = scb ^ ((srow & 7) << 4);
  const char* Ab = (const char*)A;
  const char* Bb = (const char*)Bw;
  int swz = (lr & 7) << 4;

  for (int kt = 0; kt < 12; ++kt) {
    size_t kbB = (size_t)kt * 128;
    __syncthreads();
    #pragma unroll
    for (int it = 0; it < 4; ++it) {         // A: 256 rows
      int row = srow + it * 64;
      int gr = m0 + row; if (gr >= M) gr = M - 1;
      gload16(Ab + (size_t)gr * (EMB * 2) + kbB + cbs, Asb + row * 128 + scb);
    }
    #pragma unroll
    for (int it = 0; it < 2; ++it) {         // B: 128 rows
      int row = srow + it * 64;
      int rb = n0 + row;
      gload16(Bb + (size_t)rb * (EMB * 2) + kbB + cbs, Bsb + row * 128 + scb);
    }
    __syncthreads();

    #pragma unroll
    for (int kk = 0; kk < 2; ++kk) {
      int cb = (kk * 64 + lg * 16) ^ swz;
      s16x8 af[4], bfr[4];
      #pragma unroll
      for (int f = 0; f < 4; ++f)
        af[f] = *reinterpret_cast<const s16x8*>(Asb + (wm * 64 + f * 16 + lr) * 128 + cb);
      #pragma unroll
      for (int f = 0; f < 4; ++f)
        bfr[f] = *reinterpret_cast<const s16x8*>(Bsb + (wn * 64 + f * 16 + lr) * 128 + cb);
      #pragma unroll
      for (int i = 0; i < 4; ++i)
        #pragma unroll
        for (int j = 0; j < 4; ++j)
          acc[i][j] = __builtin_amdgcn_mfma_f32_16x16x32_bf16(af[i], bfr[j], acc[i][j], 0, 0, 0);
    }
  }

  int mbase = m0 + wm * 64;
  int nbase = n0 + wn * 64;
  #pragma unroll
  for (int i = 0; i < 4; ++i) {
    #pragma unroll
    for (int j = 0; j < 4; ++j) {
      #pragma unroll
      for (int r = 0; r < 4; ++r) {
        int row = mbase + i * 16 + lg * 4 + r;
        int col = nbase + j * 16 + lr;
        if (row < M) {
          float v = acc[i][j][r];
          if (MODE == 0) {
            int b = row / SEQ;
            int s = row - b * SEQ;
            if (col >= 1536) {
              int rem = col - 1536;
              int h = rem >> 6, d = rem & 63;
              vt_out[((size_t)(b * NH + h) * HD + d) * SPAD + s] = (short)f2bf(v);
            } else {
              int which = (col >= 768) ? 1 : 0;
              if (which == 0) v *= 0.18033688f;
              int rem = col - which * 768;
              int h = rem >> 6, d = rem & 63;
              qk_out[(size_t)which * PLANE + ((size_t)b * NH + h) * HEADSZ + s * HD + d] =
                  (short)f2bf(v);
            }
          } else {
            out[(size_t)row * EMB + col] = v + bias[col];
          }
        }
      }
    }
  }
}

// ---------------- flash attention: KVBLK=128, T5 setprio, prescaled Q -----------
// R22: Q plane prescaled by SCL in gemm epilogue -> no per-tile scale VALU;
// C-init = -16*SCL (same offset algebra). Masking hoisted to the single
// half-tile that can exceed SEQ (t0h == 576): tiles 0-4/hf0 max kv = 575 < 577.
__launch_bounds__(256)
__global__ void attn(const short* __restrict__ qkv, const short* __restrict__ vt,
                     short* __restrict__ cat) {
  int bid = blockIdx.x;
  int wgid = (bid & 7) * 240 + (bid >> 3);   // 1920 = 8*240, bijective
  int bh = wgid / 5, qt = wgid % 5;
  int b = bh / NH, h = bh % NH;
  const short* Q   = qkv + (size_t)bh * HEADSZ;
  const char* KpB  = (const char*)(qkv + (size_t)PLANE + (size_t)bh * HEADSZ);
  const char* VtpB = (const char*)(vt + (size_t)bh * (HD * SPAD));

  __shared__ char KVs[32768];        // K[128][128B] @0 | V sub0 [64][128B] @16K | sub1 @24K
  __shared__ short Pl[4][32 * 72];

  int tid = threadIdx.x, w = tid >> 6, lane = tid & 63;
  int lr = lane & 15, lg = lane >> 4;
  int q0 = qt * 128;
  short* Pw = &Pl[w][0];

  s16x8 qf[2][2];
  #pragma unroll
  for (int rb = 0; rb < 2; ++rb) {
    int row = q0 + w * 32 + rb * 16 + lr; if (row >= SEQ) row = SEQ - 1;
    #pragma unroll
    for (int kk = 0; kk < 2; ++kk)
      qf[rb][kk] = *reinterpret_cast<const s16x8*>(&Q[row * HD + kk * 32 + lg * 8]);
  }

  int srow = tid >> 3;                  // 0..31
  int scb  = (tid & 7) * 16;
  int scbs = scb ^ ((srow & 7) << 4);
  int swz  = (lr & 7) << 4;
  int ka0  = lr * 128 + ((lg * 16) ^ swz);

  f32x4 acco[2][4] = {};
  float lsum[2] = {0.f, 0.f};
  // C-init = -16 * SCL (Q prescaled by SCL=0.125*log2e in gemm epilogue)
  const f32x4 NEGC = {-2.8853903f, -2.8853903f, -2.8853903f, -2.8853903f};

  for (int tt = 0; tt < 5; ++tt) {
    int t0 = tt * 128;

    __syncthreads();
    #pragma unroll
    for (int it = 0; it < 4; ++it) {
      int row = srow + it * 32;
      int grow = t0 + row; if (grow > 576) grow = 576;
      gload16(KpB + (size_t)grow * 128 + scbs, KVs + row * 128 + scb);
    }
    #pragma unroll
    for (int it = 0; it < 4; ++it) {
      int vsub = it >> 1;
      int d = srow + (it & 1) * 32;
      gload16(VtpB + (size_t)d * 1280 + (size_t)t0 * 2 + vsub * 128 + scbs,
              KVs + 16384 + vsub * 8192 + d * 128 + scb);
    }
    __syncthreads();

    #pragma unroll
    for (int hf = 0; hf < 2; ++hf) {
      const char* Ksb = KVs + hf * 8192;
      const char* Vsb = KVs + 16384 + hf * 8192;
      int t0h = t0 + hf * 64;
      bool needMask = (t0h == 576);            // only tile 4, hf=1

      #pragma unroll
      for (int fk = 0; fk < 4; ++fk) {
        s16x8 kf0 = *reinterpret_cast<const s16x8*>(Ksb + fk * 2048 + ka0);
        s16x8 kf1 = *reinterpret_cast<const s16x8*>(Ksb + fk * 2048 + (ka0 ^ 64));
        f32x4 s0 = NEGC, s1 = NEGC;
        __builtin_amdgcn_s_setprio(1);            // T5: favor MFMA burst
        s0 = __builtin_amdgcn_mfma_f32_16x16x32_bf16(kf0, qf[0][0], s0, 0, 0, 0);
        s0 = __builtin_amdgcn_mfma_f32_16x16x32_bf16(kf1, qf[0][1], s0, 0, 0, 0);
        s1 = __builtin_amdgcn_mfma_f32_16x16x32_bf16(kf0, qf[1][0], s1, 0, 0, 0);
        s1 = __builtin_amdgcn_mfma_f32_16x16x32_bf16(kf1, qf[1][1], s1, 0, 0, 0);
        __builtin_amdgcn_s_setprio(0);
        if (needMask) {
          #pragma unroll
          for (int r = 0; r < 4; ++r) {
            bool ok = (t0h + fk * 16 + lg * 4 + r) < SEQ;
            s0[r] = ok ? s0[r] : -1e30f;
            s1[r] = ok ? s1[r] : -1e30f;
          }
        }
        {
          float p0 = fexp2(s0[0]), p1 = fexp2(s0[1]);
          float p2 = fexp2(s0[2]), p3 = fexp2(s0[3]);
          lsum[0] += (p0 + p1) + (p2 + p3);
          uint2 pk; pk.x = pk2bf(p0, p1); pk.y = pk2bf(p2, p3);
          *reinterpret_cast<uint2*>(&Pw[(size_t)lr * 72 + fk * 16 + lg * 4]) = pk;
        }
        {
          float p0 = fexp2(s1[0]), p1 = fexp2(s1[1]);
          float p2 = fexp2(s1[2]), p3 = fexp2(s1[3]);
          lsum[1] += (p0 + p1) + (p2 + p3);
          uint2 pk; pk.x = pk2bf(p0, p1); pk.y = pk2bf(p2, p3);
          *reinterpret_cast<uint2*>(&Pw[(size_t)(16 + lr) * 72 + fk * 16 + lg * 4]) = pk;
        }
      }

      s16x8 pf[2][2];
      #pragma unroll
      for (int rb = 0; rb < 2; ++rb)
        #pragma unroll
        for (int kk = 0; kk < 2; ++kk)
          pf[rb][kk] = *reinterpret_cast<const s16x8*>(&Pw[(rb * 16 + lr) * 72 + kk * 32 + lg * 8]);

      #pragma unroll
      for (int f = 0; f < 4; ++f) {
        s16x8 vf0 = *reinterpret_cast<const s16x8*>(Vsb + f * 2048 + ka0);
        s16x8 vf1 = *reinterpret_cast<const s16x8*>(Vsb + f * 2048 + (ka0 ^ 64));
        __builtin_amdgcn_s_setprio(1);            // T5: favor MFMA burst
        acco[0][f] = __builtin_amdgcn_mfma_f32_16x16x32_bf16(pf[0][0], vf0, acco[0][f], 0, 0, 0);
        acco[0][f] = __builtin_amdgcn_mfma_f32_16x16x32_bf16(pf[0][1], vf1, acco[0][f], 0, 0, 0);
        acco[1][f] = __builtin_amdgcn_mfma_f32_16x16x32_bf16(pf[1][0], vf0, acco[1][f], 0, 0, 0);
        acco[1][f] = __builtin_amdgcn_mfma_f32_16x16x32_bf16(pf[1][1], vf1, acco[1][f], 0, 0, 0);
        __builtin_amdgcn_s_setprio(0);
      }
    }
  }

  #pragma unroll
  for (int rb = 0; rb < 2; ++rb) {
    lsum[rb] += __shfl_xor(lsum[rb], 16);
    lsum[rb] += __shfl_xor(lsum[rb], 32);
  }

  #pragma unroll
  for (int rb = 0; rb < 2; ++rb) {
    #pragma unroll
    for (int r = 0; r < 4; ++r) {
      float li = __shfl(lsum[rb], lg * 4 + r);
      int s = q0 + w * 32 + rb * 16 + lg * 4 + r;
      if (s < SEQ) {
        float inv = 1.0f / li;
        #pragma unroll
        for (int f = 0; f < 4; ++f)
          cat[((size_t)b * SEQ + s) * EMB + h * HD + f * 16 + lr] =
              (short)f2bf(acco[rb][f][r] * inv);
      }
    }
  }
}

extern "C" void kernel_launch(void* const* d_in, const int* in_sizes, int n_in,
                              void* d_out, int out_size, void* d_ws, size_t ws_size,
                              hipStream_t stream) {
  const float* x  = (const float*)d_in[0];
  const float* wq = (const float*)d_in[1];
  const float* wk = (const float*)d_in[2];
  const float* wv = (const float*)d_in[3];
  const float* wp = (const float*)d_in[4];
  const float* bp = (const float*)d_in[5];
  float* out = (float*)d_out;

  char* ws = (char*)d_ws;
  short* xb   = (short*)ws;                         // 28,360,704 B (reused as cat)
  short* wqkv = (short*)(ws + 28360704);            //  3,538,944 B
  short* wpb  = (short*)(ws + 31899648);            //  1,179,648 B
  short* qkb  = (short*)(ws + 33079296);            // 56,721,408 B (Q,K planes)
  short* vtb  = (short*)(ws + 89800704);            // 31,457,280 B (V^T [bh][d][640])
  short* cat  = xb;                                 // x dead after QKV GEMM

  prologue<<<8844, 256, 0, stream>>>(x, wq, wk, wv, wp, xb, wqkv, wpb, vtb);
  gemm128<0><<<145 * 18, 512, 0, stream>>>(xb, wqkv, qkb, vtb, nullptr, nullptr, TOK, 18);
  attn<<<1920, 256, 0, stream>>>(qkb, vtb, cat);
  gemm256<1><<<73 * 6, 512, 0, stream>>>(cat, wpb, nullptr, nullptr, out, bp, TOK, 6);
}